// Round 4
// baseline (219.354 us; speedup 1.0000x reference)
//
#include <hip/hip_runtime.h>
#include <math.h>

#define LN_EPS 1e-3f

__device__ __forceinline__ float silu_f(float x) { return x / (1.f + expf(-x)); }

__device__ __forceinline__ int mism1(float a, float s) {
    unsigned ua = __float_as_uint(a);
    unsigned ub = __float_as_uint(a + s);
    return (int)((ua ^ ub) >> 31);
}

// ---------------- Kernel 1: conv1 split-K partial GEMM (vectorized LDS)
// grid = 5 seq * 20 ptiles(32 pos) * 8 kchunks(64 ci) = 800 blocks, 256 threads.
__global__ __launch_bounds__(256) void k_conv1p(
    const float* __restrict__ values,   // (4,1920,512)
    const float* __restrict__ symbols,  // (1920,512)
    const float* __restrict__ w1,       // (5,512,128)
    float* __restrict__ part)           // (8,3200,128)
{
    const int T_IN = 1920, E = 512;
    int kc    = blockIdx.x & 7;
    int ptile = (blockIdx.x >> 3) % 20;
    int seq   = blockIdx.x / (8 * 20);
    int t0  = ptile * 32;
    int ci0 = kc * 64;
    const float* x = (seq < 4) ? (values + (size_t)seq * T_IN * E) : symbols;
    int p0 = 3 * t0 - 1;

    __shared__ float xs[98][64];

    int tid  = threadIdx.x;
    int c4   = tid & 31;   // co = 4*c4
    int trow = tid >> 5;   // 0..7

    for (int idx = tid; idx < 98 * 16; idx += 256) {
        int p = idx >> 4, g = idx & 15;
        int gp = p0 + p;
        float4 v = make_float4(0.f, 0.f, 0.f, 0.f);
        if (gp >= 0 && gp < T_IN)
            v = *(const float4*)(x + (size_t)gp * E + ci0 + 4 * g);
        *(float4*)&xs[p][4 * g] = v;
    }
    __syncthreads();

    float acc[4][4];
    #pragma unroll
    for (int k = 0; k < 4; k++)
        #pragma unroll
        for (int e = 0; e < 4; e++) acc[k][e] = 0.f;

    const float* wbase = w1 + (size_t)ci0 * 128 + 4 * c4;

    for (int cq = 0; cq < 64; cq += 4) {
        float4 xv[14];
        #pragma unroll
        for (int m = 0; m < 14; m++)
            xv[m] = *(const float4*)&xs[12 * trow + m][cq];
        const float* xf = (const float*)xv;
        #pragma unroll
        for (int q = 0; q < 4; q++) {
            #pragma unroll
            for (int kw = 0; kw < 5; kw++) {
                float4 w = *(const float4*)(wbase + ((size_t)kw * 512 + cq + q) * 128);
                #pragma unroll
                for (int dt = 0; dt < 4; dt++) {
                    float xvv = xf[(3 * dt + kw) * 4 + q];
                    acc[dt][0] += xvv * w.x;
                    acc[dt][1] += xvv * w.y;
                    acc[dt][2] += xvv * w.z;
                    acc[dt][3] += xvv * w.w;
                }
            }
        }
    }

    #pragma unroll
    for (int dt = 0; dt < 4; dt++) {
        int t = t0 + 4 * trow + dt;
        *(float4*)(part + (((size_t)kc * 3200 + seq * 640 + t)) * 128 + 4 * c4) =
            make_float4(acc[dt][0], acc[dt][1], acc[dt][2], acc[dt][3]);
    }
}

// ---------------- Kernel 2: fused conv1-reduce+LN1+SiLU staging, then conv2+bias
// grid = 5 seq * 32 ttiles(4 pos) * 4 cochunks(256 co) = 640 blocks, 256 threads.
__global__ __launch_bounds__(256) void k_conv2f(
    const float* __restrict__ part,  // (8,3200,128)
    const float* __restrict__ b1,
    const float* __restrict__ g1,
    const float* __restrict__ bt1,
    const float* __restrict__ w2,    // (3,128,1024)
    const float* __restrict__ b2,
    float* __restrict__ y2)          // (640,1024)
{
    int cc    = blockIdx.x & 3;
    int ttile = (blockIdx.x >> 2) & 31;
    int seq   = blockIdx.x >> 7;
    int t0  = ttile * 4;
    int co0 = cc * 256;

    __shared__ float xs[18][128];
    int tid = threadIdx.x;

    // stage h1 rows 5*t0 .. 5*t0+17: reduce 8 partials + bias + LN(128) + SiLU
    for (int idx = tid; idx < 18 * 32; idx += 256) {
        int p = idx >> 5, l = idx & 31;
        int pos = seq * 640 + 5 * t0 + p;
        float4 a = make_float4(0.f, 0.f, 0.f, 0.f);
        #pragma unroll
        for (int kc = 0; kc < 8; kc++) {
            float4 pv = *(const float4*)(part + (((size_t)kc * 3200 + pos)) * 128 + 4 * l);
            a.x += pv.x; a.y += pv.y; a.z += pv.z; a.w += pv.w;
        }
        float4 bias = *(const float4*)(b1 + 4 * l);
        a.x += bias.x; a.y += bias.y; a.z += bias.z; a.w += bias.w;

        float s1 = a.x + a.y + a.z + a.w;
        float s2 = a.x*a.x + a.y*a.y + a.z*a.z + a.w*a.w;
        #pragma unroll
        for (int m = 16; m >= 1; m >>= 1) {
            s1 += __shfl_xor(s1, m, 64);
            s2 += __shfl_xor(s2, m, 64);
        }
        float mean = s1 * (1.f / 128.f);
        float var  = s2 * (1.f / 128.f) - mean * mean;
        float rs   = rsqrtf(var + LN_EPS);
        float4 gam = *(const float4*)(g1 + 4 * l);
        float4 bet = *(const float4*)(bt1 + 4 * l);
        float4 o;
        o.x = silu_f((a.x - mean) * rs * gam.x + bet.x);
        o.y = silu_f((a.y - mean) * rs * gam.y + bet.y);
        o.z = silu_f((a.z - mean) * rs * gam.z + bet.z);
        o.w = silu_f((a.w - mean) * rs * gam.w + bet.w);
        *(float4*)&xs[p][4 * l] = o;
    }
    __syncthreads();

    int c4   = tid & 63;
    int trow = tid >> 6;
    int co = co0 + 4 * c4;

    float acc[4] = {0.f, 0.f, 0.f, 0.f};
    const float* wbase = w2 + co;

    for (int cq = 0; cq < 128; cq += 4) {
        float4 x0 = *(const float4*)&xs[5 * trow + 0][cq];
        float4 x1 = *(const float4*)&xs[5 * trow + 1][cq];
        float4 x2 = *(const float4*)&xs[5 * trow + 2][cq];
        const float* xf0 = (const float*)&x0;
        const float* xf1 = (const float*)&x1;
        const float* xf2 = (const float*)&x2;
        #pragma unroll
        for (int q = 0; q < 4; q++) {
            float4 w0 = *(const float4*)(wbase + ((size_t)(0 * 128 + cq + q)) * 1024);
            float4 w1v = *(const float4*)(wbase + ((size_t)(1 * 128 + cq + q)) * 1024);
            float4 w2v = *(const float4*)(wbase + ((size_t)(2 * 128 + cq + q)) * 1024);
            float a0 = xf0[q], a1 = xf1[q], a2 = xf2[q];
            acc[0] += a0 * w0.x + a1 * w1v.x + a2 * w2v.x;
            acc[1] += a0 * w0.y + a1 * w1v.y + a2 * w2v.y;
            acc[2] += a0 * w0.z + a1 * w1v.z + a2 * w2v.z;
            acc[3] += a0 * w0.w + a1 * w1v.w + a2 * w2v.w;
        }
    }

    float4 bias = *(const float4*)(b2 + co);
    float4 out = make_float4(acc[0] + bias.x, acc[1] + bias.y,
                             acc[2] + bias.z, acc[3] + bias.w);
    int pos = seq * 128 + t0 + trow;
    *(float4*)(y2 + (size_t)pos * 1024 + co) = out;
}

// ---------------- Kernel 3: LN(1024) + SiLU -> vp / sp
__global__ __launch_bounds__(256) void k_ln2(
    const float* __restrict__ y2,   // (640,1024)
    const float* __restrict__ g2,
    const float* __restrict__ bt2,
    float* __restrict__ vp,         // (512,1024)
    float* __restrict__ sp)         // (128,1024)
{
    int pos = blockIdx.x;
    int tid = threadIdx.x, lane = tid & 63, wv = tid >> 6;
    __shared__ float red[4][2];

    float4 a = *(const float4*)(y2 + (size_t)pos * 1024 + 4 * tid);
    float s1 = a.x + a.y + a.z + a.w;
    float s2 = a.x*a.x + a.y*a.y + a.z*a.z + a.w*a.w;
    #pragma unroll
    for (int m = 32; m >= 1; m >>= 1) {
        s1 += __shfl_xor(s1, m, 64);
        s2 += __shfl_xor(s2, m, 64);
    }
    if (lane == 0) { red[wv][0] = s1; red[wv][1] = s2; }
    __syncthreads();
    float S1 = red[0][0] + red[1][0] + red[2][0] + red[3][0];
    float S2 = red[0][1] + red[1][1] + red[2][1] + red[3][1];
    float mean = S1 * (1.f / 1024.f);
    float var  = S2 * (1.f / 1024.f) - mean * mean;
    float rs   = rsqrtf(var + LN_EPS);

    float4 gam = *(const float4*)(g2 + 4 * tid);
    float4 bet = *(const float4*)(bt2 + 4 * tid);
    float4 out;
    out.x = silu_f((a.x - mean) * rs * gam.x + bet.x);
    out.y = silu_f((a.y - mean) * rs * gam.y + bet.y);
    out.z = silu_f((a.z - mean) * rs * gam.z + bet.z);
    out.w = silu_f((a.w - mean) * rs * gam.w + bet.w);
    if (pos < 512)
        *(float4*)(vp + (size_t)pos * 1024 + 4 * tid) = out;
    else
        *(float4*)(sp + (size_t)(pos - 512) * 1024 + 4 * tid) = out;
}

// ---------------- Kernel 4: mismatch counts
// grid = 4b * 128j = 512 blocks, 256 threads: thread = (i = tid&127, half = tid>>7)
__global__ __launch_bounds__(256) void k_attn_cnt(
    const float* __restrict__ vp,   // (512,1024)
    const float* __restrict__ sp,   // (128,1024)
    int* __restrict__ cnt)          // (4,128,128)
{
    int b = blockIdx.x >> 7;
    int j = blockIdx.x & 127;
    int tid = threadIdx.x;
    int i = tid & 127, half = tid >> 7;

    const float* vrow = vp + ((size_t)(b * 128 + i)) * 1024 + half * 512;
    const float* srow = sp + (size_t)j * 1024 + half * 512;

    int m = 0;
    #pragma unroll 8
    for (int k = 0; k < 128; k++) {
        float4 v = *(const float4*)(vrow + 4 * k);
        float4 s = *(const float4*)(srow + 4 * k);
        m += mism1(v.x, s.x) + mism1(v.y, s.y) + mism1(v.z, s.z) + mism1(v.w, s.w);
    }

    __shared__ int cc[2][128];
    cc[half][i] = m;
    __syncthreads();
    if (tid < 128)
        cnt[((size_t)b * 128 + j) * 128 + tid] = cc[0][tid] + cc[1][tid];
}

// ---------------- Kernel 5: softmax (per wave) + einsum + silu
// grid = 4b * 32 jquad * 4 dquarter = 512 blocks, 256 threads.
__global__ __launch_bounds__(256) void k_attn_out(
    const int*   __restrict__ cnt,  // (4,128,128)
    const float* __restrict__ vp,   // (512,1024)
    const float* __restrict__ sp,   // (128,1024)
    float* __restrict__ O)          // (4,128,1024)
{
    int b  = blockIdx.x >> 7;
    int r  = blockIdx.x & 127;
    int j0 = (r >> 2) * 4;
    int d0 = (r & 3) * 256;
    int tid = threadIdx.x, lane = tid & 63, w = tid >> 6;
    int j = j0 + w;

    __shared__ float sc[4][128];

    const int* crow = cnt + ((size_t)b * 128 + j) * 128;
    int c0 = crow[lane], c1 = crow[lane + 64];
    float S0 = 1.f - (float)c0 * (2.f / 1024.f);
    float S1 = 1.f - (float)c1 * (2.f / 1024.f);
    float mx = fmaxf(S0, S1);
    #pragma unroll
    for (int m = 32; m >= 1; m >>= 1) mx = fmaxf(mx, __shfl_xor(mx, m, 64));
    float e0 = expf(S0 - mx), e1 = expf(S1 - mx);
    float sm = e0 + e1;
    #pragma unroll
    for (int m = 32; m >= 1; m >>= 1) sm += __shfl_xor(sm, m, 64);
    float inv = 1.f / sm;
    sc[w][lane]      = e0 * inv;
    sc[w][lane + 64] = e1 * inv;
    __syncthreads();

    int dd = d0 + 4 * lane;
    const float* vpb = vp + (size_t)b * 131072;
    float4 ao = make_float4(0.f, 0.f, 0.f, 0.f);
    #pragma unroll 4
    for (int i = 0; i < 128; i++) {
        float4 v = *(const float4*)(vpb + (size_t)i * 1024 + dd);
        float f = sc[w][i];
        ao.x += f * v.x; ao.y += f * v.y; ao.z += f * v.z; ao.w += f * v.w;
    }
    float4 s = *(const float4*)(sp + (size_t)j * 1024 + dd);
    float4 o;
    o.x = silu_f(ao.x * s.x);
    o.y = silu_f(ao.y * s.y);
    o.z = silu_f(ao.z * s.z);
    o.w = silu_f(ao.w * s.w);
    *(float4*)(O + ((size_t)b * 128 + j) * 1024 + dd) = o;
}

extern "C" void kernel_launch(void* const* d_in, const int* in_sizes, int n_in,
                              void* d_out, int out_size, void* d_ws, size_t ws_size,
                              hipStream_t stream) {
    const float* values  = (const float*)d_in[0];
    const float* symbols = (const float*)d_in[1];
    const float* conv1_w = (const float*)d_in[2];
    const float* conv1_b = (const float*)d_in[3];
    const float* ln1_g   = (const float*)d_in[4];
    const float* ln1_b   = (const float*)d_in[5];
    const float* conv2_w = (const float*)d_in[6];
    const float* conv2_b = (const float*)d_in[7];
    const float* ln2_g   = (const float*)d_in[8];
    const float* ln2_b   = (const float*)d_in[9];

    float* out = (float*)d_out;
    float* O   = out;                       // (4,128,1024)
    float* vp  = out + 4 * 128 * 1024;      // (4,128,1024)

    float* part = (float*)d_ws;             // (8,3200,128)
    float* y2   = part + 8 * 3200 * 128;    // (640,1024)
    float* sp   = y2 + 640 * 1024;          // (128,1024)
    int*   cnt  = (int*)(sp + 128 * 1024);  // (4,128,128)

    k_conv1p<<<800, 256, 0, stream>>>(values, symbols, conv1_w, part);
    k_conv2f<<<640, 256, 0, stream>>>(part, conv1_b, ln1_g, ln1_b, conv2_w, conv2_b, y2);
    k_ln2<<<640, 256, 0, stream>>>(y2, ln2_g, ln2_b, vp, sp);
    k_attn_cnt<<<512, 256, 0, stream>>>(vp, sp, cnt);
    k_attn_out<<<512, 256, 0, stream>>>(cnt, vp, sp, O);
}

// Round 5
// 188.985 us; speedup vs baseline: 1.1607x; 1.1607x over previous
//
#include <hip/hip_runtime.h>
#include <math.h>

#define LN_EPS 1e-3f

typedef __attribute__((ext_vector_type(8))) short short8;
typedef __attribute__((ext_vector_type(4))) float floatx4;

__device__ __forceinline__ float silu_f(float x) { return x / (1.f + expf(-x)); }

__device__ __forceinline__ int mism1(float a, float s) {
    unsigned ua = __float_as_uint(a);
    unsigned ub = __float_as_uint(a + s);
    return (int)((ua ^ ub) >> 31);
}

__device__ __forceinline__ short f2bf(float f) {
    unsigned u = __float_as_uint(f);
    unsigned r = (u + 0x7FFFu + ((u >> 16) & 1u)) >> 16;
    return (short)r;
}

// ---------------- Kernel 0: swizzle conv1 weights into B-fragment order, bf16
// wt_sw[kc(8)][ks(10)][nt(8)][lane(64)][j(8)]; B[n][k]: n=nt*16+(lane&15),
// kw=ks>>1, ci=kc*64+(ks&1)*32+(lane>>4)*8+j. 327,680 elements total.
__global__ __launch_bounds__(256) void k_prep(
    const float* __restrict__ w1,   // (5,512,128)
    short* __restrict__ wt_sw)
{
    int tid = blockIdx.x * 256 + threadIdx.x;
    int j    = tid & 7;
    int lane = (tid >> 3) & 63;
    int nt   = (tid >> 9) & 7;
    int ks   = (tid >> 12) % 10;
    int kc   = tid / 40960;
    int kw = ks >> 1;
    int ci = kc * 64 + (ks & 1) * 32 + ((lane >> 4) & 3) * 8 + j;
    int n  = nt * 16 + (lane & 15);
    wt_sw[tid] = f2bf(w1[((size_t)(kw * 512 + ci)) * 128 + n]);
}

// ---------------- Kernel 1: conv1 as bf16 MFMA GEMM, split-K over 8 ci-chunks
// grid = 50 Mtiles(64 pos) * 8 kc = 400 blocks, 256 threads (4 waves, 2x2).
// Wave computes 32 pos x 64 co via 2x4 tiles of 16x16; K_chunk = 5kw*64ci = 320.
__global__ __launch_bounds__(256) void k_conv1m(
    const float* __restrict__ values,   // (4,1920,512)
    const float* __restrict__ symbols,  // (1920,512)
    const short* __restrict__ wt_sw,
    float* __restrict__ part)           // (8,3200,128)
{
    int kc = blockIdx.x & 7;
    int mt = blockIdx.x >> 3;            // 0..49
    int seq = mt / 10;
    int t0  = (mt % 10) * 64;            // within-seq
    const float* x = (seq < 4) ? (values + (size_t)seq * 1920 * 512) : symbols;
    int p0 = 3 * t0 - 1;

    __shared__ short xs[194 * 72];       // rows r=3*t_local+kw (0..193) x 64ci (+8 pad)

    int tid = threadIdx.x;
    // stage x tile: fp32 -> bf16 LDS
    for (int idx = tid; idx < 194 * 16; idx += 256) {
        int r = idx >> 4, g = idx & 15;
        int gp = p0 + r;
        float4 v = make_float4(0.f, 0.f, 0.f, 0.f);
        if (gp >= 0 && gp < 1920)
            v = *(const float4*)(x + (size_t)gp * 512 + kc * 64 + 4 * g);
        short* d = xs + r * 72 + 4 * g;
        d[0] = f2bf(v.x); d[1] = f2bf(v.y); d[2] = f2bf(v.z); d[3] = f2bf(v.w);
    }
    __syncthreads();

    int lane = tid & 63;
    int w    = tid >> 6;
    int wm   = w & 1;      // m half: 32 pos
    int wn   = w >> 1;     // n half: 64 co
    int quad = lane >> 4;
    int mrow = lane & 15;

    floatx4 acc[2][4];
    #pragma unroll
    for (int mi = 0; mi < 2; mi++)
        #pragma unroll
        for (int ni = 0; ni < 4; ni++)
            acc[mi][ni] = (floatx4){0.f, 0.f, 0.f, 0.f};

    #pragma unroll 2
    for (int ks = 0; ks < 10; ks++) {
        int kw  = ks >> 1;
        int ci0 = (ks & 1) * 32;
        short8 a[2];
        #pragma unroll
        for (int mi = 0; mi < 2; mi++) {
            int r = 3 * (wm * 32 + mi * 16 + mrow) + kw;
            a[mi] = *(const short8*)(xs + r * 72 + ci0 + quad * 8);
        }
        #pragma unroll
        for (int ni = 0; ni < 4; ni++) {
            int nt = wn * 4 + ni;
            short8 b = *(const short8*)(wt_sw +
                ((((size_t)kc * 10 + ks) * 8 + nt) * 64 + lane) * 8);
            #pragma unroll
            for (int mi = 0; mi < 2; mi++)
                acc[mi][ni] = __builtin_amdgcn_mfma_f32_16x16x32_bf16(
                    a[mi], b, acc[mi][ni], 0, 0, 0);
        }
    }

    // epilogue: D row = quad*4+reg, col = lane&15  (m89-verified)
    #pragma unroll
    for (int mi = 0; mi < 2; mi++) {
        #pragma unroll
        for (int ni = 0; ni < 4; ni++) {
            int co = wn * 64 + ni * 16 + mrow;
            #pragma unroll
            for (int reg = 0; reg < 4; reg++) {
                int pos = mt * 64 + wm * 32 + mi * 16 + quad * 4 + reg;
                part[((size_t)kc * 3200 + pos) * 128 + co] = acc[mi][ni][reg];
            }
        }
    }
}

// ---------------- Kernel 2: fused conv1-reduce+LN1+SiLU staging, then conv2+bias
// grid = 5 seq * 32 ttiles(4 pos) * 4 cochunks(256 co) = 640 blocks, 256 threads.
__global__ __launch_bounds__(256) void k_conv2f(
    const float* __restrict__ part,  // (8,3200,128)
    const float* __restrict__ b1,
    const float* __restrict__ g1,
    const float* __restrict__ bt1,
    const float* __restrict__ w2,    // (3,128,1024)
    const float* __restrict__ b2,
    float* __restrict__ y2)          // (640,1024)
{
    int cc    = blockIdx.x & 3;
    int ttile = (blockIdx.x >> 2) & 31;
    int seq   = blockIdx.x >> 7;
    int t0  = ttile * 4;
    int co0 = cc * 256;

    __shared__ float xs[18][128];
    int tid = threadIdx.x;

    for (int idx = tid; idx < 18 * 32; idx += 256) {
        int p = idx >> 5, l = idx & 31;
        int pos = seq * 640 + 5 * t0 + p;
        float4 a = make_float4(0.f, 0.f, 0.f, 0.f);
        #pragma unroll
        for (int kc = 0; kc < 8; kc++) {
            float4 pv = *(const float4*)(part + (((size_t)kc * 3200 + pos)) * 128 + 4 * l);
            a.x += pv.x; a.y += pv.y; a.z += pv.z; a.w += pv.w;
        }
        float4 bias = *(const float4*)(b1 + 4 * l);
        a.x += bias.x; a.y += bias.y; a.z += bias.z; a.w += bias.w;

        float s1 = a.x + a.y + a.z + a.w;
        float s2 = a.x*a.x + a.y*a.y + a.z*a.z + a.w*a.w;
        #pragma unroll
        for (int m = 16; m >= 1; m >>= 1) {
            s1 += __shfl_xor(s1, m, 64);
            s2 += __shfl_xor(s2, m, 64);
        }
        float mean = s1 * (1.f / 128.f);
        float var  = s2 * (1.f / 128.f) - mean * mean;
        float rs   = rsqrtf(var + LN_EPS);
        float4 gam = *(const float4*)(g1 + 4 * l);
        float4 bet = *(const float4*)(bt1 + 4 * l);
        float4 o;
        o.x = silu_f((a.x - mean) * rs * gam.x + bet.x);
        o.y = silu_f((a.y - mean) * rs * gam.y + bet.y);
        o.z = silu_f((a.z - mean) * rs * gam.z + bet.z);
        o.w = silu_f((a.w - mean) * rs * gam.w + bet.w);
        *(float4*)&xs[p][4 * l] = o;
    }
    __syncthreads();

    int c4   = tid & 63;
    int trow = tid >> 6;
    int co = co0 + 4 * c4;

    float acc[4] = {0.f, 0.f, 0.f, 0.f};
    const float* wbase = w2 + co;

    for (int cq = 0; cq < 128; cq += 4) {
        float4 x0 = *(const float4*)&xs[5 * trow + 0][cq];
        float4 x1 = *(const float4*)&xs[5 * trow + 1][cq];
        float4 x2 = *(const float4*)&xs[5 * trow + 2][cq];
        const float* xf0 = (const float*)&x0;
        const float* xf1 = (const float*)&x1;
        const float* xf2 = (const float*)&x2;
        #pragma unroll
        for (int q = 0; q < 4; q++) {
            float4 w0 = *(const float4*)(wbase + ((size_t)(0 * 128 + cq + q)) * 1024);
            float4 w1v = *(const float4*)(wbase + ((size_t)(1 * 128 + cq + q)) * 1024);
            float4 w2v = *(const float4*)(wbase + ((size_t)(2 * 128 + cq + q)) * 1024);
            float a0 = xf0[q], a1 = xf1[q], a2 = xf2[q];
            acc[0] += a0 * w0.x + a1 * w1v.x + a2 * w2v.x;
            acc[1] += a0 * w0.y + a1 * w1v.y + a2 * w2v.y;
            acc[2] += a0 * w0.z + a1 * w1v.z + a2 * w2v.z;
            acc[3] += a0 * w0.w + a1 * w1v.w + a2 * w2v.w;
        }
    }

    float4 bias = *(const float4*)(b2 + co);
    float4 out = make_float4(acc[0] + bias.x, acc[1] + bias.y,
                             acc[2] + bias.z, acc[3] + bias.w);
    int pos = seq * 128 + t0 + trow;
    *(float4*)(y2 + (size_t)pos * 1024 + co) = out;
}

// ---------------- Kernel 3: LN(1024) + SiLU -> vp / sp
__global__ __launch_bounds__(256) void k_ln2(
    const float* __restrict__ y2,   // (640,1024)
    const float* __restrict__ g2,
    const float* __restrict__ bt2,
    float* __restrict__ vp,         // (512,1024)
    float* __restrict__ sp)         // (128,1024)
{
    int pos = blockIdx.x;
    int tid = threadIdx.x, lane = tid & 63, wv = tid >> 6;
    __shared__ float red[4][2];

    float4 a = *(const float4*)(y2 + (size_t)pos * 1024 + 4 * tid);
    float s1 = a.x + a.y + a.z + a.w;
    float s2 = a.x*a.x + a.y*a.y + a.z*a.z + a.w*a.w;
    #pragma unroll
    for (int m = 32; m >= 1; m >>= 1) {
        s1 += __shfl_xor(s1, m, 64);
        s2 += __shfl_xor(s2, m, 64);
    }
    if (lane == 0) { red[wv][0] = s1; red[wv][1] = s2; }
    __syncthreads();
    float S1 = red[0][0] + red[1][0] + red[2][0] + red[3][0];
    float S2 = red[0][1] + red[1][1] + red[2][1] + red[3][1];
    float mean = S1 * (1.f / 1024.f);
    float var  = S2 * (1.f / 1024.f) - mean * mean;
    float rs   = rsqrtf(var + LN_EPS);

    float4 gam = *(const float4*)(g2 + 4 * tid);
    float4 bet = *(const float4*)(bt2 + 4 * tid);
    float4 out;
    out.x = silu_f((a.x - mean) * rs * gam.x + bet.x);
    out.y = silu_f((a.y - mean) * rs * gam.y + bet.y);
    out.z = silu_f((a.z - mean) * rs * gam.z + bet.z);
    out.w = silu_f((a.w - mean) * rs * gam.w + bet.w);
    if (pos < 512)
        *(float4*)(vp + (size_t)pos * 1024 + 4 * tid) = out;
    else
        *(float4*)(sp + (size_t)(pos - 512) * 1024 + 4 * tid) = out;
}

// ---------------- Kernel 4: mismatch counts
__global__ __launch_bounds__(256) void k_attn_cnt(
    const float* __restrict__ vp,   // (512,1024)
    const float* __restrict__ sp,   // (128,1024)
    int* __restrict__ cnt)          // (4,128,128)
{
    int b = blockIdx.x >> 7;
    int j = blockIdx.x & 127;
    int tid = threadIdx.x;
    int i = tid & 127, half = tid >> 7;

    const float* vrow = vp + ((size_t)(b * 128 + i)) * 1024 + half * 512;
    const float* srow = sp + (size_t)j * 1024 + half * 512;

    int m = 0;
    #pragma unroll 8
    for (int k = 0; k < 128; k++) {
        float4 v = *(const float4*)(vrow + 4 * k);
        float4 s = *(const float4*)(srow + 4 * k);
        m += mism1(v.x, s.x) + mism1(v.y, s.y) + mism1(v.z, s.z) + mism1(v.w, s.w);
    }

    __shared__ int cc[2][128];
    cc[half][i] = m;
    __syncthreads();
    if (tid < 128)
        cnt[((size_t)b * 128 + j) * 128 + tid] = cc[0][tid] + cc[1][tid];
}

// ---------------- Kernel 5: softmax (per wave) + einsum + silu
__global__ __launch_bounds__(256) void k_attn_out(
    const int*   __restrict__ cnt,  // (4,128,128)
    const float* __restrict__ vp,   // (512,1024)
    const float* __restrict__ sp,   // (128,1024)
    float* __restrict__ O)          // (4,128,1024)
{
    int b  = blockIdx.x >> 7;
    int r  = blockIdx.x & 127;
    int j0 = (r >> 2) * 4;
    int d0 = (r & 3) * 256;
    int tid = threadIdx.x, lane = tid & 63, w = tid >> 6;
    int j = j0 + w;

    __shared__ float sc[4][128];

    const int* crow = cnt + ((size_t)b * 128 + j) * 128;
    int c0 = crow[lane], c1 = crow[lane + 64];
    float S0 = 1.f - (float)c0 * (2.f / 1024.f);
    float S1 = 1.f - (float)c1 * (2.f / 1024.f);
    float mx = fmaxf(S0, S1);
    #pragma unroll
    for (int m = 32; m >= 1; m >>= 1) mx = fmaxf(mx, __shfl_xor(mx, m, 64));
    float e0 = expf(S0 - mx), e1 = expf(S1 - mx);
    float sm = e0 + e1;
    #pragma unroll
    for (int m = 32; m >= 1; m >>= 1) sm += __shfl_xor(sm, m, 64);
    float inv = 1.f / sm;
    sc[w][lane]      = e0 * inv;
    sc[w][lane + 64] = e1 * inv;
    __syncthreads();

    int dd = d0 + 4 * lane;
    const float* vpb = vp + (size_t)b * 131072;
    float4 ao = make_float4(0.f, 0.f, 0.f, 0.f);
    #pragma unroll 4
    for (int i = 0; i < 128; i++) {
        float4 v = *(const float4*)(vpb + (size_t)i * 1024 + dd);
        float f = sc[w][i];
        ao.x += f * v.x; ao.y += f * v.y; ao.z += f * v.z; ao.w += f * v.w;
    }
    float4 s = *(const float4*)(sp + (size_t)j * 1024 + dd);
    float4 o;
    o.x = silu_f(ao.x * s.x);
    o.y = silu_f(ao.y * s.y);
    o.z = silu_f(ao.z * s.z);
    o.w = silu_f(ao.w * s.w);
    *(float4*)(O + ((size_t)b * 128 + j) * 1024 + dd) = o;
}

extern "C" void kernel_launch(void* const* d_in, const int* in_sizes, int n_in,
                              void* d_out, int out_size, void* d_ws, size_t ws_size,
                              hipStream_t stream) {
    const float* values  = (const float*)d_in[0];
    const float* symbols = (const float*)d_in[1];
    const float* conv1_w = (const float*)d_in[2];
    const float* conv1_b = (const float*)d_in[3];
    const float* ln1_g   = (const float*)d_in[4];
    const float* ln1_b   = (const float*)d_in[5];
    const float* conv2_w = (const float*)d_in[6];
    const float* conv2_b = (const float*)d_in[7];
    const float* ln2_g   = (const float*)d_in[8];
    const float* ln2_b   = (const float*)d_in[9];

    float* out = (float*)d_out;
    float* O   = out;                       // (4,128,1024)
    float* vp  = out + 4 * 128 * 1024;      // (4,128,1024)

    float* part  = (float*)d_ws;              // (8,3200,128)  = 3,276,800 f
    float* y2    = part + 8 * 3200 * 128;     // (640,1024)
    float* sp    = y2 + 640 * 1024;           // (128,1024)
    int*   cnt   = (int*)(sp + 128 * 1024);   // (4,128,128)
    short* wt_sw = (short*)(cnt + 4 * 128 * 128);  // 327,680 bf16

    k_prep<<<1280, 256, 0, stream>>>(conv1_w, wt_sw);
    k_conv1m<<<400, 256, 0, stream>>>(values, symbols, wt_sw, part);
    k_conv2f<<<640, 256, 0, stream>>>(part, conv1_b, ln1_g, ln1_b, conv2_w, conv2_b, y2);
    k_ln2<<<640, 256, 0, stream>>>(y2, ln2_g, ln2_b, vp, sp);
    k_attn_cnt<<<512, 256, 0, stream>>>(vp, sp, cnt);
    k_attn_out<<<512, 256, 0, stream>>>(cnt, vp, sp, O);
}